// Round 5
// baseline (951.049 us; speedup 1.0000x reference)
//
#include <hip/hip_runtime.h>

// Koopman operator: z' = z + DT*(z@A^T + ((z@Vf)*a)@Uf), 8 steps fused.
// Column-parallel, weight-register-stationary, 4-REGION ROTATED PIPELINE:
//   block = 512 threads = 8 waves, 64 rows/block, 1 block/CU (reg-bound).
//   Wave w owns output col-tiles {2w, 2w+1}; waves 0..5 own proj tile l=w.
//   Step = 4 barrier-delimited regions R[rg]; phase-2 lags by one region:
//     R[rg]: pfread p[rg-1] | A^T+proj MFMA on zf[rg] (prefetched last
//            region) | zfread rg+1 | P2[rg-1] MFMA | scatter rg-1 | bar
//   Every region's LDS reads are prefetch for the NEXT region, hidden under
//   this region's MFMA. Single z_lds buffer: write of new z[rgX] (region
//   4s+X+1) and last read of old z[rgX] (region 4s+X-1) are always >=2
//   barriers apart; all intra-region row ranges are disjoint.

typedef __bf16 bf16_t;
typedef __bf16 bf16x8 __attribute__((ext_vector_type(8)));
typedef float f32x4 __attribute__((ext_vector_type(4)));

#define DT_C   0.1f
#define BMAX_C 0.3f

#define ZP 264   // z_lds row pitch (elems)
#define PP 104   // p_lds row pitch
#define AP 9     // a_lds row pitch (floats)

#define WT1_ELEMS (352 * 256)
#define WT2_ELEMS (256 * 96)

// ---------------- dtype detector --------------------------------------------
__global__ void detect_dtype(const unsigned int* __restrict__ Abits,
                             int* __restrict__ flag) {
  if (threadIdx.x == 0 && blockIdx.x == 0) {
    int plausible = 0;
    for (int i = 0; i < 64; ++i) {
      unsigned int w = Abits[i];
      int e0 = (int)((w >> 7) & 0xFFu);
      int e1 = (int)((w >> 23) & 0xFFu);
      plausible += (e0 >= 100 && e0 <= 133);
      plausible += (e1 >= 100 && e1 <= 133);
    }
    *flag = (plausible >= 112) ? 1 : 0;  // 1 = bf16 storage, 0 = fp32
  }
}

// ---------------- prep: fold tanh clamp + DT into transposed bf16 weights ---
template <typename T, int MODE>
__global__ __launch_bounds__(256) void prep_weights(
    const int* __restrict__ flag, const T* __restrict__ A,
    const T* __restrict__ BU, const T* __restrict__ BV,
    bf16_t* __restrict__ wt1, bf16_t* __restrict__ wt2) {
  if (*flag != MODE) return;
  int idx = blockIdx.x * 256 + threadIdx.x;
  if (idx < WT1_ELEMS) {
    int i = idx >> 8;          // 0..351
    int j = idx & 255;
    float v;
    if (i < 256) {
      v = DT_C * (float)A[i * 256 + j];
    } else {
      int c = i - 256, l = c >> 4, r = c & 15;
      v = BMAX_C * tanhf((float)BV[(l * 256 + j) * 16 + r]);
    }
    wt1[idx] = (bf16_t)v;
  } else {
    int k = idx - WT1_ELEMS;
    if (k < WT2_ELEMS) {
      int i = k / 96, c = k % 96;
      int l = c >> 4, r = c & 15;
      wt2[k] = (bf16_t)(DT_C * BMAX_C * tanhf((float)BU[(l * 256 + i) * 16 + r]));
    }
  }
}

// ---------------- fused 8-step propagation ----------------------------------
template <typename T, int MODE>
__global__ __launch_bounds__(512, 2) void koopman_kernel(
    const int* __restrict__ flag, const T* __restrict__ zg,
    const T* __restrict__ ag, const int* __restrict__ steps_p,
    const bf16_t* __restrict__ wt1, const bf16_t* __restrict__ wt2,
    T* __restrict__ outg) {
  if (*flag != MODE) return;

  __shared__ __align__(16) bf16_t z_lds[64 * ZP];
  __shared__ __align__(16) bf16_t p_lds[64 * PP];
  __shared__ float a_lds[64 * AP];

  const int tid = threadIdx.x;
  const int wave = tid >> 6;       // 0..7
  const int lane = tid & 63;
  const int col = lane & 15;       // MFMA n / C-col
  const int quad = lane >> 4;      // MFMA lane quad
  const long long row0 = (long long)blockIdx.x * 64;
  const int ct0 = wave * 2;        // owned col-tiles: ct0, ct0+1

  // ---- stage a into LDS (fp32, step-invariant) ---------------------------
  for (int t = tid; t < 64 * 6; t += 512) {
    int r = t / 6, l = t % 6;
    a_lds[r * AP + l] = (float)ag[(row0 + r) * 6 + l];
  }

  // ---- weight fragments: register-resident for the whole kernel ----------
  bf16x8 w1f[3][8];   // [0]/[1]: A^T tiles ct0/ct0+1; [2]: proj tile (wave<6)
  bf16x8 w2f[2][3];
#pragma unroll
  for (int kk = 0; kk < 8; ++kk) {
    w1f[0][kk] = *(const bf16x8*)&wt1[(size_t)(ct0 * 16 + col) * 256 + kk * 32 + quad * 8];
    w1f[1][kk] = *(const bf16x8*)&wt1[(size_t)((ct0 + 1) * 16 + col) * 256 + kk * 32 + quad * 8];
  }
  if (wave < 6) {
#pragma unroll
    for (int kk = 0; kk < 8; ++kk)
      w1f[2][kk] = *(const bf16x8*)&wt1[(size_t)(256 + wave * 16 + col) * 256 + kk * 32 + quad * 8];
  }
#pragma unroll
  for (int kk = 0; kk < 3; ++kk) {
    w2f[0][kk] = *(const bf16x8*)&wt2[(size_t)(ct0 * 16 + col) * 96 + kk * 32 + quad * 8];
    w2f[1][kk] = *(const bf16x8*)&wt2[(size_t)((ct0 + 1) * 16 + col) * 96 + kk * 32 + quad * 8];
  }

  // ---- z master: fp32 C-layout regs for owned col-tiles, all 64 rows -----
  f32x4 zacc[2][4];
#pragma unroll
  for (int t = 0; t < 2; ++t)
#pragma unroll
    for (int rg = 0; rg < 4; ++rg)
#pragma unroll
      for (int reg = 0; reg < 4; ++reg)
        zacc[t][rg][reg] =
            (float)zg[(row0 + rg * 16 + quad * 4 + reg) * 256 + (ct0 + t) * 16 + col];

  const int steps = steps_p[0];

#define SCATTER_RG(rg_)                                                       \
  {                                                                           \
    _Pragma("unroll") for (int t = 0; t < 2; ++t)                             \
        _Pragma("unroll") for (int reg = 0; reg < 4; ++reg)                   \
            z_lds[((rg_)*16 + quad * 4 + reg) * ZP + (ct0 + t) * 16 + col] =  \
                (bf16_t)zacc[t][rg_][reg];                                    \
  }

#define LOADZ8(dst, rg_)                                                      \
  {                                                                           \
    _Pragma("unroll") for (int kk = 0; kk < 8; ++kk)(dst)[kk] =               \
        *(const bf16x8*)&z_lds[((rg_)*16 + col) * ZP + kk * 32 + quad * 8];   \
  }

#define LOADP3(dst, rg_)                                                      \
  {                                                                           \
    _Pragma("unroll") for (int kk = 0; kk < 3; ++kk)(dst)[kk] =               \
        *(const bf16x8*)&p_lds[((rg_)*16 + col) * PP + kk * 32 + quad * 8];   \
  }

  // One region of the rotated pipeline. RG_ is compile-time.
  //  pfread p[PRG] | A^T+proj MFMA (zb) | zfread (RG+1)&3 -> zb |
  //  p-write RG | P2[PRG] (pfb) | scatter PRG | bar
#define REGION(RG_, DO_P2)                                                    \
  {                                                                           \
    constexpr int RG = (RG_);                                                 \
    constexpr int PRG = ((RG_) + 3) & 3;                                      \
    bf16x8 pfb[3];                                                            \
    if (DO_P2) LOADP3(pfb, PRG);                                              \
    f32x4 a0 = zacc[0][RG], a1 = zacc[1][RG];                                 \
    f32x4 pr = {0.f, 0.f, 0.f, 0.f};                                          \
    __builtin_amdgcn_s_setprio(1);                                            \
    if (wave < 6) {                                                           \
      _Pragma("unroll") for (int kk = 0; kk < 8; ++kk) {                      \
        a0 = __builtin_amdgcn_mfma_f32_16x16x32_bf16(zb[kk], w1f[0][kk], a0, 0, 0, 0); \
        a1 = __builtin_amdgcn_mfma_f32_16x16x32_bf16(zb[kk], w1f[1][kk], a1, 0, 0, 0); \
        pr = __builtin_amdgcn_mfma_f32_16x16x32_bf16(zb[kk], w1f[2][kk], pr, 0, 0, 0); \
      }                                                                       \
    } else {                                                                  \
      _Pragma("unroll") for (int kk = 0; kk < 8; ++kk) {                      \
        a0 = __builtin_amdgcn_mfma_f32_16x16x32_bf16(zb[kk], w1f[0][kk], a0, 0, 0, 0); \
        a1 = __builtin_amdgcn_mfma_f32_16x16x32_bf16(zb[kk], w1f[1][kk], a1, 0, 0, 0); \
      }                                                                       \
    }                                                                         \
    __builtin_amdgcn_s_setprio(0);                                            \
    zacc[0][RG] = a0;                                                         \
    zacc[1][RG] = a1;                                                         \
    LOADZ8(zb, (RG + 1) & 3); /* prefetch next region's zf (WAR on zb) */     \
    if (wave < 6) {                                                           \
      p_lds[(RG * 16 + quad * 4 + 0) * PP + wave * 16 + col] =                \
          (bf16_t)(pr[0] * a_lds[(RG * 16 + quad * 4 + 0) * AP + wave]);      \
      p_lds[(RG * 16 + quad * 4 + 1) * PP + wave * 16 + col] =                \
          (bf16_t)(pr[1] * a_lds[(RG * 16 + quad * 4 + 1) * AP + wave]);      \
      p_lds[(RG * 16 + quad * 4 + 2) * PP + wave * 16 + col] =                \
          (bf16_t)(pr[2] * a_lds[(RG * 16 + quad * 4 + 2) * AP + wave]);      \
      p_lds[(RG * 16 + quad * 4 + 3) * PP + wave * 16 + col] =                \
          (bf16_t)(pr[3] * a_lds[(RG * 16 + quad * 4 + 3) * AP + wave]);      \
    }                                                                         \
    if (DO_P2) {                                                              \
      f32x4 b0 = zacc[0][PRG], b1 = zacc[1][PRG];                             \
      __builtin_amdgcn_s_setprio(1);                                          \
      _Pragma("unroll") for (int kk = 0; kk < 3; ++kk) {                      \
        b0 = __builtin_amdgcn_mfma_f32_16x16x32_bf16(pfb[kk], w2f[0][kk], b0, 0, 0, 0); \
        b1 = __builtin_amdgcn_mfma_f32_16x16x32_bf16(pfb[kk], w2f[1][kk], b1, 0, 0, 0); \
      }                                                                       \
      __builtin_amdgcn_s_setprio(0);                                          \
      zacc[0][PRG] = b0;                                                      \
      zacc[1][PRG] = b1;                                                      \
      SCATTER_RG(PRG);                                                        \
    }                                                                         \
    __syncthreads();                                                          \
  }

  // prologue: scatter initial z (z_0), make visible, prefetch zf rg0
  SCATTER_RG(0); SCATTER_RG(1); SCATTER_RG(2); SCATTER_RG(3);
  __syncthreads();
  bf16x8 zb[8];
  LOADZ8(zb, 0);

  for (int s = 0; s < steps; ++s) {
    REGION(0, (s > 0))
    REGION(1, true)
    REGION(2, true)
    REGION(3, true)
  }

  // epilogue: finish P2[3] of the last step, then store
  {
    bf16x8 pfb[3];
    LOADP3(pfb, 3);
    f32x4 b0 = zacc[0][3], b1 = zacc[1][3];
#pragma unroll
    for (int kk = 0; kk < 3; ++kk) {
      b0 = __builtin_amdgcn_mfma_f32_16x16x32_bf16(pfb[kk], w2f[0][kk], b0, 0, 0, 0);
      b1 = __builtin_amdgcn_mfma_f32_16x16x32_bf16(pfb[kk], w2f[1][kk], b1, 0, 0, 0);
    }
    zacc[0][3] = b0;
    zacc[1][3] = b1;
  }

#pragma unroll
  for (int t = 0; t < 2; ++t)
#pragma unroll
    for (int rg = 0; rg < 4; ++rg)
#pragma unroll
      for (int reg = 0; reg < 4; ++reg)
        outg[(row0 + rg * 16 + quad * 4 + reg) * 256 + (ct0 + t) * 16 + col] =
            (T)zacc[t][rg][reg];
#undef SCATTER_RG
#undef LOADZ8
#undef LOADP3
#undef REGION
}

extern "C" void kernel_launch(void* const* d_in, const int* in_sizes, int n_in,
                              void* d_out, int out_size, void* d_ws,
                              size_t ws_size, hipStream_t stream) {
  const void* z = d_in[0];
  const void* a = d_in[1];
  const void* A = d_in[2];
  const void* BU = d_in[3];
  const void* BV = d_in[4];
  const int* steps = (const int*)d_in[5];

  int* flag = (int*)d_ws;
  bf16_t* wt1 = (bf16_t*)((char*)d_ws + 16);
  bf16_t* wt2 = wt1 + WT1_ELEMS;

  const int N = in_sizes[0] / 256;  // 262144 rows

  detect_dtype<<<1, 64, 0, stream>>>((const unsigned int*)A, flag);

  prep_weights<float, 0><<<448, 256, 0, stream>>>(
      flag, (const float*)A, (const float*)BU, (const float*)BV, wt1, wt2);
  prep_weights<bf16_t, 1><<<448, 256, 0, stream>>>(
      flag, (const bf16_t*)A, (const bf16_t*)BU, (const bf16_t*)BV, wt1, wt2);

  koopman_kernel<float, 0><<<N / 64, 512, 0, stream>>>(
      flag, (const float*)z, (const float*)a, steps, wt1, wt2, (float*)d_out);
  koopman_kernel<bf16_t, 1><<<N / 64, 512, 0, stream>>>(
      flag, (const bf16_t*)z, (const bf16_t*)a, steps, wt1, wt2,
      (bf16_t*)d_out);
}